// Round 10
// baseline (316.897 us; speedup 1.0000x reference)
//
#include <hip/hip_runtime.h>
#include <hip/hip_bf16.h>
#include <stdint.h>

typedef __attribute__((ext_vector_type(8)))  __bf16 bf16x8;
typedef __attribute__((ext_vector_type(4)))  float  f32x4;
typedef __attribute__((ext_vector_type(16))) float  f32x16;

#define KP 4160   // padded K: 4096 (quantized x) + 32 (lora T) + 32 zeros = 65 tiles of 64

__device__ inline void async_copy16(const void* g, void* l) {
  __builtin_amdgcn_global_load_lds((const __attribute__((address_space(1))) void*)g,
                                   (__attribute__((address_space(3))) void*)l, 16, 0, 0);
}

// ---------------------------------------------------------------------------
// Kernel 1 (FULL-K restructure, r9 post-mortem: prep is latency-bound at 15%
// HBM / 11% VALU — fix with ILP + no Tp round-trip):
// 256 blocks x 512 thr; block owns rows [16*bx,+16) x ALL 4096 cols.
//  Part A: quant — thread t: row m0+(t>>5), 8 independent 16-col blocks
//          (cb0=t&31, +32i).  8-deep ILP vs r9's 2.
//  Part B: loraT — 8 waves x 512-col windows, 16 MFMA k-steps each; 8
//          partials reduced in LDS; T -> bf16 Ab[:,4096:4128] + zero pad
//          DIRECTLY (Tp buffer + k2 reduce pass deleted).
// Quant math bit-exact (closed-form level select, verified r3).
// ---------------------------------------------------------------------------
__global__ __launch_bounds__(512) void fused_quant_lora_kernel(
    const float* __restrict__ x, const float* __restrict__ ss,
    const float* __restrict__ la, __bf16* __restrict__ Ab) {
  __shared__ float red[8][16][32];
  int tid = threadIdx.x;
  int m0  = blockIdx.x << 4;                  // 16-row strip

  // ---- Part A: quant, 8 col-blocks per thread ----
  {
    int row = m0 + (tid >> 5);
    int cb0 = tid & 31;
#pragma unroll
    for (int i = 0; i < 8; i++) {
      int col = (cb0 + (i << 5)) << 4;
      const float4* xp = (const float4*)(x + ((size_t)row << 12) + col);
      const float4* sp = (const float4*)(ss + col);
      float xs[16];
#pragma unroll
      for (int j = 0; j < 4; j++) {
        float4 xv = xp[j]; float4 sv = sp[j];
        xs[4*j+0] = xv.x * sv.x; xs[4*j+1] = xv.y * sv.y;
        xs[4*j+2] = xv.z * sv.z; xs[4*j+3] = xv.w * sv.w;
      }
      float amax = 0.f;
#pragma unroll
      for (int j = 0; j < 16; j++) amax = fmaxf(amax, fabsf(xs[j]));
      amax = fmaxf(amax, 1e-12f);
      float scale = amax / 6.0f;              // IEEE fp32 divide, same as np
      bf16x8 o0, o1;
#pragma unroll
      for (int j = 0; j < 16; j++) {
        float a  = fabsf(xs[j]);
        float xn = a / scale;                 // IEEE fp32 divide, same as np
        float lvl;
        if (xn < 2.25f) {
          // 0.5-grid nearest, tie -> lower (== argmin first-on-tie, verified r3)
          lvl = 0.5f * __builtin_ceilf(__builtin_fmaf(2.0f, xn, -0.5f));
        } else {
          lvl = (xn <= 2.5f) ? 2.0f : (xn <= 3.5f) ? 3.0f
              : (xn <= 5.0f) ? 4.0f : 6.0f;
        }
        float mag = lvl * scale;
        float q = (xs[j] > 0.f) ? mag : ((xs[j] < 0.f) ? -mag : 0.f);
        if (j < 8) o0[j] = (__bf16)q; else o1[j-8] = (__bf16)q;
      }
      __bf16* dst = Ab + (size_t)row * KP + col;
      *(bf16x8*)dst = o0;
      *(bf16x8*)(dst + 8) = o1;
    }
  }

  // ---- Part B: loraT full-K (verified fragment layout r1-r5/r4-loraT) ----
  {
    int wave = tid >> 6, lane = tid & 63;
    int lrow = lane & 15, kg = lane >> 4;
    f32x4 acc0 = {0.f,0.f,0.f,0.f}, acc1 = {0.f,0.f,0.f,0.f};
    const float* xrow = x + ((size_t)(m0 + lrow) << 12);
    const float* a0   = la + ((size_t)lrow << 12);
    const float* a1   = a0 + (16 << 12);
#pragma unroll 4
    for (int k0 = 0; k0 < 16; k0++) {
      int kk = (wave << 9) + (k0 << 5) + (kg << 3);
      float xv[8], sv[8], v0[8], v1[8];
      *(float4*)&xv[0] = *(const float4*)(xrow + kk);
      *(float4*)&xv[4] = *(const float4*)(xrow + kk + 4);
      *(float4*)&sv[0] = *(const float4*)(ss + kk);
      *(float4*)&sv[4] = *(const float4*)(ss + kk + 4);
      *(float4*)&v0[0] = *(const float4*)(a0 + kk);
      *(float4*)&v0[4] = *(const float4*)(a0 + kk + 4);
      *(float4*)&v1[0] = *(const float4*)(a1 + kk);
      *(float4*)&v1[4] = *(const float4*)(a1 + kk + 4);
      bf16x8 af, b0, b1;
#pragma unroll
      for (int j = 0; j < 8; j++) {
        af[j] = (__bf16)(xv[j] * sv[j]);
        b0[j] = (__bf16)v0[j];
        b1[j] = (__bf16)v1[j];
      }
      acc0 = __builtin_amdgcn_mfma_f32_16x16x32_bf16(af, b0, acc0, 0, 0, 0);
      acc1 = __builtin_amdgcn_mfma_f32_16x16x32_bf16(af, b1, acc1, 0, 0, 0);
    }
#pragma unroll
    for (int r = 0; r < 4; r++) {
      red[wave][kg*4 + r][lrow]      = acc0[r];   // verified layout (r1-r5)
      red[wave][kg*4 + r][16 + lrow] = acc1[r];
    }
    __syncthreads();
    // 512 threads -> one T element each; write bf16 + zero pad directly.
    int rr = tid >> 5, cc = tid & 31;
    float s = 0.f;
#pragma unroll
    for (int wv = 0; wv < 8; wv++) s += red[wv][rr][cc];
    __bf16* dst = Ab + (size_t)(m0 + rr) * KP + 4096;
    dst[cc]      = (__bf16)s;
    dst[32 + cc] = (__bf16)0.f;
  }
}

// ---------------------------------------------------------------------------
// Kernel 2 (wconv only, streaming restructure): block = 2 rows; thread t
// handles groups {t, t+256} (both <512 -> hot path has NO integer divide,
// no branches); threads 0-7 do the tail: lora_b (g 512-515), zeros (516-519).
// Per thread: 32B load + 8 cvt + 16B store.  Pure BW.
// ---------------------------------------------------------------------------
__global__ __launch_bounds__(256) void wconv_kernel(const float* __restrict__ w,
                                                    const float* __restrict__ lb,
                                                    __bf16* __restrict__ Bb) {
  int tid = threadIdx.x;
#pragma unroll
  for (int r = 0; r < 2; r++) {
    int row = (blockIdx.x << 1) + r;
    const float* wr = w + ((size_t)row << 12);
    __bf16*      br = Bb + (size_t)row * KP;
#pragma unroll
    for (int gi = 0; gi < 2; gi++) {
      int g = tid + (gi << 8);                // 0..511: always w data
      const float4* wp = (const float4*)(wr + (g << 3));
      float4 a = wp[0], bb = wp[1];
      bf16x8 v;
      v[0]=(__bf16)a.x;  v[1]=(__bf16)a.y;  v[2]=(__bf16)a.z;  v[3]=(__bf16)a.w;
      v[4]=(__bf16)bb.x; v[5]=(__bf16)bb.y; v[6]=(__bf16)bb.z; v[7]=(__bf16)bb.w;
      *(bf16x8*)(br + ((size_t)g << 3)) = v;
    }
    if (tid < 8) {                            // tail: lora_b + zero pad
      int g = 512 + tid;
      bf16x8 v;
      if (g < 516) {
        const float* p = lb + (size_t)row * 32 + ((g - 512) << 3);
#pragma unroll
        for (int j = 0; j < 8; j++) v[j] = (__bf16)p[j];
      } else {
#pragma unroll
        for (int j = 0; j < 8; j++) v[j] = (__bf16)0.f;
      }
      *(bf16x8*)(br + ((size_t)g << 3)) = v;
    }
  }
}

// ---------------------------------------------------------------------------
// Kernel 3: r9 gemm VERBATIM (verified: 120us, MfmaUtil 53%, conflicts 0).
// 256x256 8-phase, 32x32x16 MFMA, half-wave bank-spread fix (r9).
// ---------------------------------------------------------------------------
#define GBAR() __builtin_amdgcn_s_barrier()
#define PRI1() __builtin_amdgcn_s_setprio(1)
#define PRI0() __builtin_amdgcn_s_setprio(0)
#define WVM(n) asm volatile("s_waitcnt vmcnt(" #n ")" ::: "memory")

#define STG(srcb, dstb, bb, h, t) do {                                         \
    const __bf16* _s = (srcb) + (size_t)(h) * (128 * (size_t)KP)               \
                              + ((size_t)(t) << 6);                            \
    char* _d = (dstb) + ((bb) << 15) + ((h) << 14);                            \
    async_copy16(_s, _d);                                                      \
    async_copy16(_s + 32, _d + 1024);                                          \
  } while (0)

#define KOFF(KS) ((((KS) >> 1) << 10) + ((((KS) & 1) << 5) ^ sx))

#define RD_A(base, KS) do { _Pragma("unroll")                                  \
  for (int mf = 0; mf < 4; mf++)                                               \
    af[mf] = *(const bf16x8*)((base) + (mf << 12) + KOFF(KS)); } while (0)

#define RD_B(base, KS) do {                                                    \
    Br[0*4 + (KS)] = *(const bf16x8*)((base) + KOFF(KS));                      \
    Br[1*4 + (KS)] = *(const bf16x8*)((base) + 4096 + KOFF(KS)); } while (0)

#define MM8(KS) do { _Pragma("unroll")                                         \
  for (int mf = 0; mf < 4; mf++) _Pragma("unroll")                             \
  for (int nf = 0; nf < 2; nf++)                                               \
    acc[mf][nf] = __builtin_amdgcn_mfma_f32_32x32x16_bf16(                     \
        af[mf], Br[nf*4 + (KS)], acc[mf][nf], 0, 0, 0); } while (0)

__global__ __launch_bounds__(512, 2) void gemm_kernel(const __bf16* __restrict__ A,
                                                      const __bf16* __restrict__ B,
                                                      const float* __restrict__ bias,
                                                      float* __restrict__ C) {
  extern __shared__ char lds[];                // 131072 B: A[2x32K] | B[2x32K]
  const int tid  = threadIdx.x;
  const int w    = tid >> 6, lane = tid & 63;
  const int ln31 = lane & 31, kg2 = lane >> 5;
  const int wm   = w >> 2, wn = w & 3;
  const int bid  = blockIdx.x;
  const int sbid = ((bid & 7) << 5) | (bid >> 3);  // XCD swizzle (256%8==0)
  const int bm   = sbid >> 4, bn = sbid & 15;
  const size_t m0 = (size_t)bm << 8, n0 = (size_t)bn << 8;

  // staging source (per-thread, inverse-swizzled); ^(w&1) = row-bit4 slot XOR
  const int rr = (w << 4) + (lane >> 2);
  const int kk = ((lane & 3) ^ (((lane >> 5) & 1) << 1) ^ (w & 1)) << 3;
  const __bf16* aS = A + (m0 + rr) * (size_t)KP + kk;
  const __bf16* bS = B + (n0 + rr) * (size_t)KP + kk;
  char* dA = lds + (w << 11);
  char* dB = lds + 65536 + (w << 11);

  // fragment read pointers; k-slot bit4 = kg2 ^ row-bit4 (r9 conflict fix)
  const int sx  = (lane & 8) << 2;             // row-bit3 XOR (byte bit5)
  const int k16 = ((kg2 ^ ((ln31 >> 4) & 1)) << 4);  // row-bit4 XOR (byte bit4)
  const int cA = ((ln31 >> 4) << 11) + ((ln31 & 15) << 6) + k16;
  const int cB = ((((wn & 1) << 2) + (ln31 >> 4)) << 11)
               + ((ln31 & 15) << 6) + k16;
  const char* pA0 = lds + (wm << 14) + cA;
  const char* pA1 = pA0 + 32768;
  const char* pB0 = lds + 65536 + ((wn >> 1) << 14) + cB;
  const char* pB1 = pB0 + 32768;

  bf16x8 af[4], Br[8];
  f32x16 acc[4][2];
#pragma unroll
  for (int i = 0; i < 4; i++)
#pragma unroll
    for (int j = 0; j < 2; j++)
#pragma unroll
      for (int q = 0; q < 16; q++) acc[i][j][q] = 0.f;

  // prologue: tile0 -> buf0, tile1.B -> buf1; t0 landed, t1.B in flight.
  STG(bS, dB, 0, 0, 0); STG(bS, dB, 0, 1, 0);
  STG(aS, dA, 0, 0, 0); STG(aS, dA, 0, 1, 0);
  STG(bS, dB, 1, 0, 1); STG(bS, dB, 1, 1, 1);
  WVM(4);
  GBAR();

#pragma unroll 1
  for (int i = 0; i < 32; i++) {
    const int t1 = 2*i + 1, t2 = 2*i + 2;
    int t3 = 2*i + 3; if (t3 > 64) t3 = 64;    // stray (unread) restage, in-bounds
    // ---- tile 2i (buf0) ----
    STG(aS, dA, 1, 0, t1);                     // p0
    RD_B(pB0, 0); RD_B(pB0, 1); RD_A(pA0, 0);
    PRI1(); MM8(0); PRI0();
    GBAR();
    STG(aS, dA, 1, 1, t1);                     // p1
    RD_B(pB0, 2); RD_B(pB0, 3); RD_A(pA0, 1);
    PRI1(); MM8(1); PRI0();
    GBAR();
    STG(bS, dB, 0, 0, t2);                     // p2  (buf0.B reads done by p1)
    RD_A(pA0, 2);
    PRI1(); MM8(2); PRI0();
    GBAR();
    STG(bS, dB, 0, 1, t2);                     // p3
    RD_A(pA0, 3);
    PRI1(); MM8(3); PRI0();
    WVM(4);                                    // gate: buf1 (t1) landed
    GBAR();
    // ---- tile 2i+1 (buf1) ----
    STG(aS, dA, 0, 0, t2);                     // p4  (buf0.A reads done by p3)
    RD_B(pB1, 0); RD_B(pB1, 1); RD_A(pA1, 0);
    PRI1(); MM8(0); PRI0();
    GBAR();
    STG(aS, dA, 0, 1, t2);                     // p5
    RD_B(pB1, 2); RD_B(pB1, 3); RD_A(pA1, 1);
    PRI1(); MM8(1); PRI0();
    GBAR();
    STG(bS, dB, 1, 0, t3);                     // p6  (buf1.B reads done by p5)
    RD_A(pA1, 2);
    PRI1(); MM8(2); PRI0();
    GBAR();
    STG(bS, dB, 1, 1, t3);                     // p7
    RD_A(pA1, 3);
    PRI1(); MM8(3); PRI0();
    WVM(4);                                    // gate: buf0 (t2) landed
    GBAR();
  }

  // epilogue: tile 64 (buf0), staged during last iter p2-p5, gated at p7.
  RD_B(pB0, 0); RD_B(pB0, 1); RD_B(pB0, 2); RD_B(pB0, 3);
  RD_A(pA0, 0); PRI1(); MM8(0); PRI0();
  RD_A(pA0, 1); PRI1(); MM8(1); PRI0();
  RD_A(pA0, 2); PRI1(); MM8(2); PRI0();
  RD_A(pA0, 3); PRI1(); MM8(3); PRI0();

  // C-write: + bias, fp32.  col=lane&31, row=(q&3)+8*(q>>2)+4*kg2.
  const int    colb = (int)n0 + (wn << 6) + ln31;
  const size_t rowb = m0 + ((size_t)wm << 7) + (kg2 << 2);
#pragma unroll
  for (int nf = 0; nf < 2; nf++) {
    const int col = colb + (nf << 5);
    const float bv = bias[col];
#pragma unroll
    for (int mf = 0; mf < 4; mf++) {
      const size_t r0 = rowb + ((size_t)mf << 5);
#pragma unroll
      for (int q = 0; q < 16; q++) {
        const size_t row = r0 + (q & 3) + ((q >> 2) << 3);
        C[row * 4096 + col] = acc[mf][nf][q] + bv;
      }
    }
  }
}

extern "C" void kernel_launch(void* const* d_in, const int* in_sizes, int n_in,
                              void* d_out, int out_size, void* d_ws, size_t ws_size,
                              hipStream_t stream) {
  const float* x    = (const float*)d_in[0];   // [2,2048,4096]
  const float* ss   = (const float*)d_in[1];   // [4096]
  const float* w    = (const float*)d_in[2];   // [4096,4096]
  const float* la   = (const float*)d_in[3];   // [32,4096]
  const float* lb   = (const float*)d_in[4];   // [4096,32]
  const float* bias = (const float*)d_in[5];   // [4096]
  float* out = (float*)d_out;                  // [2,2048,4096] fp32

  __bf16* Ab = (__bf16*)d_ws;                  // [4096, 4160] bf16  (34.1 MB)
  __bf16* Bb = Ab + (size_t)4096 * KP;         // [4096, 4160] bf16  (34.1 MB)

  static bool s_attr = false;
  if (!s_attr) {                               // config call, not a stream op
    hipFuncSetAttribute((const void*)gemm_kernel,
                        hipFuncAttributeMaxDynamicSharedMemorySize, 131072);
    s_attr = true;
  }

  fused_quant_lora_kernel<<<256, 512, 0, stream>>>(x, ss, la, Ab);
  wconv_kernel<<<2048, 256, 0, stream>>>(w, lb, Bb);
  gemm_kernel<<<256, 512, 131072, stream>>>(Ab, Bb, bias, out);
}